// Round 14
// baseline (350.411 us; speedup 1.0000x reference)
//
#include <hip/hip_runtime.h>
#include <math.h>

// Problem constants
#define NB 8
#define CC 512
#define NPIX 4096   // 64*64
#define HM 256

// Workspace layout (4-byte units). Total ~130.4 MiB.
// bf16 "planes": hi-plane and lo-plane of the Markidis split stored separately
// (R13: removes the ~190 VALU unpack ops/tile that made R12 VALU-bound).
#define WS_MS    0                  // [8][4096] m_s (f32)
#define WS_MBG   32768              // [8][4096] m_bg (f32)
#define WS_DIST  65536              // [8][4096] EDT (f32)
#define WS_CNT   98304              // [16]
#define WS_PC    98320              // [8][512] p_contrast (f32)
#define WS_GWH   102416             // [512][512] gate_w hi (ushort)
#define WS_GWL   233488             // [512][512] gate_w lo
#define WS_FWH   364560             // [512][512] fusion_w hi
#define WS_FWL   495632             // [512][512] fusion_w lo
#define WS_FSH   626704             // [8][4096][512] f_s hi ([p][c] layout!)
#define WS_FSL   9015312            // [8][4096][512] f_s lo
#define WS_FPH   17403920           // [8][4096][512] f_pur hi
#define WS_FPL   25792528           // [8][4096][512] f_pur lo

typedef __attribute__((ext_vector_type(8))) short short8;
typedef __attribute__((ext_vector_type(4))) float f32x4;

// ---- bf16 split: x ~= hi + lo, both RNE bf16 ------------------------------
__device__ __forceinline__ uint32_t packbf(float x) {
    uint32_t b = __float_as_uint(x);
    uint32_t hi = (b + 0x7fffu + ((b >> 16) & 1u)) & 0xffff0000u;
    float rem = x - __uint_as_float(hi);
    uint32_t rb = __float_as_uint(rem);
    uint32_t lo = (rb + 0x7fffu + ((rb >> 16) & 1u)) >> 16;
    return hi | lo;   // hi<<16 | lo
}
__device__ __forceinline__ float joinbf(uint32_t h, uint32_t l) {
    return __uint_as_float(h << 16) + __uint_as_float(l << 16);
}

__device__ __forceinline__ float wave_sum(float v) {
#pragma unroll
    for (int o = 32; o > 0; o >>= 1) v += __shfl_down(v, o, 64);
    return v;
}
__device__ __forceinline__ float wave_max(float v) {
#pragma unroll
    for (int o = 32; o > 0; o >>= 1) v = fmaxf(v, __shfl_down(v, o, 64));
    return v;
}

// ---------------------------------------------------------------------------
// K0: mask prep + exact EDT (one block per batch, all in LDS). 1024 threads.
// ---------------------------------------------------------------------------
__global__ __launch_bounds__(1024) void mask_edt_kernel(
    const int* __restrict__ mask, float* __restrict__ ms, float* __restrict__ mbg,
    float* __restrict__ dist, float* __restrict__ cnt)
{
    __shared__ float sm[4096];
    __shared__ float sg[4096];
    __shared__ float red[32];

    const int b = blockIdx.x;
    const int t = threadIdx.x;
    const int wid = t >> 6, lane = t & 63;
    const int* mb = mask + b * (HM * HM);

#pragma unroll
    for (int u = 0; u < 4; ++u) {
        int p = u * 1024 + t;
        int i = p >> 6, j = p & 63;
        sm[p] = (float)mb[(i * 4) * HM + (j * 4)];
    }
    __syncthreads();

    float cfg = 0.f, cbg = 0.f;
#pragma unroll
    for (int u = 0; u < 4; ++u) {
        int p = u * 1024 + t;
        int i = p >> 6, j = p & 63;
        float mx = 0.f;
#pragma unroll
        for (int di = -1; di <= 1; ++di) {
            int ii = i + di;
            if (ii < 0 || ii > 63) continue;
#pragma unroll
            for (int dj = -1; dj <= 1; ++dj) {
                int jj = j + dj;
                if (jj < 0 || jj > 63) continue;
                mx = fmaxf(mx, sm[ii * 64 + jj]);
            }
        }
        float m = sm[p];
        float bg = fmaxf(mx - m, 0.f);
        cfg += m; cbg += bg;
        ms[b * NPIX + p] = m;
        mbg[b * NPIX + p] = bg;
    }
    float s1 = wave_sum(cfg), s2 = wave_sum(cbg);
    if (lane == 0) { red[wid] = s1; red[16 + wid] = s2; }
    __syncthreads();
    if (t == 0) {
        float a = 0.f, g = 0.f;
#pragma unroll
        for (int w = 0; w < 16; ++w) { a += red[w]; g += red[16 + w]; }
        cnt[b] = a; cnt[8 + b] = g;
    }

#pragma unroll 1
    for (int u = 0; u < 4; ++u) {
        int p = u * 1024 + t;
        int i = p >> 6, j = p & 63;
        float fi = (float)i;
        float best = 1e30f;
#pragma unroll 8
        for (int ii = 0; ii < 64; ++ii) {
            float v = fabsf(fi - (float)ii) + 128.f * (1.f - sm[ii * 64 + j]);
            best = fminf(best, v);
        }
        sg[p] = best;
    }
    __syncthreads();

    float dmx = 0.f;
#pragma unroll 1
    for (int u = 0; u < 4; ++u) {
        int p = u * 1024 + t;
        int i = p >> 6, j = p & 63;
        float fj = (float)j;
        float best = 1e30f;
#pragma unroll 8
        for (int jj = 0; jj < 64; ++jj) {
            float g = sg[i * 64 + jj];
            float dj = fj - (float)jj;
            best = fminf(best, fmaf(g, g, dj * dj));
        }
        float d = sqrtf(best);
        sm[p] = d;
        dmx = fmaxf(dmx, d);
    }
    __syncthreads();
    float mW = wave_max(dmx);
    if (lane == 0) red[wid] = mW;
    __syncthreads();
    float dmax = red[0];
#pragma unroll
    for (int w = 1; w < 16; ++w) dmax = fmaxf(dmax, red[w]);
    dmax += 1e-6f;
#pragma unroll
    for (int u = 0; u < 4; ++u) {
        int p = u * 1024 + t;
        dist[b * NPIX + p] = sm[p] / dmax;
    }
}

// ---------------------------------------------------------------------------
// K1: p_contrast (fp32 exact)
// ---------------------------------------------------------------------------
__global__ __launch_bounds__(256) void pcontrast_kernel(
    const float* __restrict__ F, const float* __restrict__ ms,
    const float* __restrict__ mbg, const float* __restrict__ cnt,
    float* __restrict__ pc)
{
    const int c = blockIdx.x, b = blockIdx.y, t = threadIdx.x;
    const float4* f4 = (const float4*)(F + ((size_t)b * CC + c) * NPIX);
    const float4* m4 = (const float4*)(ms + (size_t)b * NPIX);
    const float4* g4 = (const float4*)(mbg + (size_t)b * NPIX);
    float sfg = 0.f, sbg = 0.f;
#pragma unroll 4
    for (int idx = t; idx < NPIX / 4; idx += 256) {
        float4 v = f4[idx], m = m4[idx], g = g4[idx];
        sfg += v.x * m.x + v.y * m.y + v.z * m.z + v.w * m.w;
        sbg += v.x * g.x + v.y * g.y + v.z * g.z + v.w * g.w;
    }
    __shared__ float r1[4], r2[4];
    sfg = wave_sum(sfg); sbg = wave_sum(sbg);
    int wid = t >> 6, lane = t & 63;
    if (lane == 0) { r1[wid] = sfg; r2[wid] = sbg; }
    __syncthreads();
    if (t == 0) {
        float a = r1[0] + r1[1] + r1[2] + r1[3];
        float g = r2[0] + r2[1] + r2[2] + r2[3];
        pc[b * CC + c] = a / (cnt[b] + 1e-8f) - g / (cnt[8 + b] + 1e-8f);
    }
}

// ---------------------------------------------------------------------------
// K2: transpose f_s [b][c][p] f32 -> hi/lo ushort planes [b][p][c]
// ---------------------------------------------------------------------------
__global__ __launch_bounds__(256) void transpose_pack(
    const float* __restrict__ F, ushort* __restrict__ Fh, ushort* __restrict__ Fl)
{
    __shared__ float sm[64][65];
    const int b  = blockIdx.z;
    const int c0 = blockIdx.y * 64;
    const int p0 = blockIdx.x * 64;
    const int t  = threadIdx.x;
    const float* Fb = F + ((size_t)b * CC + c0) * NPIX + p0;
#pragma unroll
    for (int s = 0; s < 4; ++s) {
        int cl = s * 16 + (t >> 4);
        float4 v = *(const float4*)&Fb[(size_t)cl * NPIX + (t & 15) * 4];
        *(float4*)&sm[cl][(t & 15) * 4] = v;
    }
    __syncthreads();
    const int lane = t & 63, w = t >> 6;
    size_t ob = ((size_t)b * NPIX + p0) * CC + c0;
#pragma unroll
    for (int s = 0; s < 16; ++s) {
        int pl = s * 4 + w;
        uint32_t u = packbf(sm[lane][pl]);
        Fh[ob + (size_t)pl * CC + lane] = (ushort)(u >> 16);
        Fl[ob + (size_t)pl * CC + lane] = (ushort)(u & 0xffffu);
    }
}

// ---------------------------------------------------------------------------
// K3: pack weights -> hi/lo planes
// ---------------------------------------------------------------------------
__global__ __launch_bounds__(256) void pack_weights(
    const float* __restrict__ gw, const float* __restrict__ fw,
    ushort* __restrict__ gwh, ushort* __restrict__ gwl,
    ushort* __restrict__ fwh, ushort* __restrict__ fwl)
{
    const int o = blockIdx.x, t = threadIdx.x;
#pragma unroll 2
    for (int c = t; c < CC; c += 256) {
        uint32_t ug = packbf(gw[o * CC + c]);
        uint32_t uf = packbf(fw[o * (CC + 1) + c]);
        gwh[o * CC + c] = (ushort)(ug >> 16); gwl[o * CC + c] = (ushort)(ug & 0xffffu);
        fwh[o * CC + c] = (ushort)(uf >> 16); fwl[o * CC + c] = (ushort)(uf & 0xffffu);
    }
}

// ---------------------------------------------------------------------------
// K4/K5: bf16-split MFMA GEMM, separate hi/lo planes (R13).
// 128x128 tile, BK=32, 16x16x32 MFMA, 2-phase double-buffer (R12 win kept).
// LDS: 8 planes of 8KB (A/B x hi/lo x dbuf) = 64KB -> 2 blocks/CU.
// Plane row = 32 bf16 = 64B; fragment = ds_read_b128 of 8 bf16 = a ready
// MFMA operand (ZERO unpack VALU). Lane spread over 16B units is even
// (8 lanes per 4-bank quad x 8 quads) -> LDS minimum-cycle class, no swizzle
// needed; staging global src is plain linear (wave = 16 rows x 64B).
// ---------------------------------------------------------------------------
#define STAGE_PLANE(dst, gsrc)                                                           \
    do {                                                                                 \
        _Pragma("unroll")                                                                \
        for (int c_ = 0; c_ < 2; ++c_) {                                                 \
            int grp_ = c_ * 4 + wid;                                                     \
            const ushort* s_ = (gsrc) + (size_t)(grp_ * 16 + (lane >> 2)) * CC           \
                               + (lane & 3) * 8;                                         \
            __builtin_amdgcn_global_load_lds(                                            \
                (const __attribute__((address_space(1))) uint32_t*)s_,                   \
                (__attribute__((address_space(3))) uint32_t*)&dst[grp_ * 256 + lane * 4],\
                16, 0, 0);                                                               \
        }                                                                                \
    } while (0)

#define STAGE_TILE(dAh, dAl, dBh, dBl, ktE)                                              \
    do {                                                                                 \
        STAGE_PLANE(dAh, Abh + (size_t)mBase * CC + (ktE));                              \
        STAGE_PLANE(dAl, Abl + (size_t)mBase * CC + (ktE));                              \
        STAGE_PLANE(dBh, Bbh + (size_t)nBase * CC + (ktE));                              \
        STAGE_PLANE(dBl, Bbl + (size_t)nBase * CC + (ktE));                              \
    } while (0)

#define COMPUTE_TILE(sAh, sAl, sBh, sBl)                                                 \
    do {                                                                                 \
        short8 hA_[4], lA_[4];                                                           \
        _Pragma("unroll")                                                                \
        for (int fm_ = 0; fm_ < 4; ++fm_) {                                              \
            int ro_ = (wr * 64 + fm_ * 16 + fr) * 32 + kc * 8;   /* ushort units */      \
            hA_[fm_] = *(const short8*)((const ushort*)sAh + ro_);                       \
            lA_[fm_] = *(const short8*)((const ushort*)sAl + ro_);                       \
        }                                                                                \
        _Pragma("unroll")                                                                \
        for (int fn_ = 0; fn_ < 4; ++fn_) {                                              \
            int ro_ = (wc * 64 + fn_ * 16 + fr) * 32 + kc * 8;                           \
            short8 hB_ = *(const short8*)((const ushort*)sBh + ro_);                     \
            short8 lB_ = *(const short8*)((const ushort*)sBl + ro_);                     \
            _Pragma("unroll")                                                            \
            for (int fm_ = 0; fm_ < 4; ++fm_) {                                          \
                acc[fm_][fn_] = __builtin_amdgcn_mfma_f32_16x16x32_bf16(hA_[fm_], hB_, acc[fm_][fn_], 0, 0, 0); \
                acc[fm_][fn_] = __builtin_amdgcn_mfma_f32_16x16x32_bf16(hA_[fm_], lB_, acc[fm_][fn_], 0, 0, 0); \
                acc[fm_][fn_] = __builtin_amdgcn_mfma_f32_16x16x32_bf16(lA_[fm_], hB_, acc[fm_][fn_], 0, 0, 0); \
            }                                                                            \
        }                                                                                \
    } while (0)

template <int MODE>
__global__ __launch_bounds__(256, 2) void mfma_gemm(
    const ushort* __restrict__ Aph, const ushort* __restrict__ Apl,
    const ushort* __restrict__ Bph, const ushort* __restrict__ Bpl,
    long aStride, long bStride,
    const float* __restrict__ bias,
    const float* __restrict__ aux,      // MODE0: pc[b][512]; MODE1: dist[b][4096]
    const float* __restrict__ wsrc,     // MODE1: fusion_w f32 (last col)
    ushort* __restrict__ oh,            // MODE0: f_pur hi plane
    ushort* __restrict__ ol,            // MODE0: f_pur lo plane
    float* __restrict__ of)             // MODE1: final output
{
    // XCD-chunked bijective swizzle (nwg=1024, %8==0) — R10-confirmed fetch win
    const int gx = gridDim.x, gy = gridDim.y;
    const int nwg = gx * gy * gridDim.z;
    int lin = (blockIdx.z * gy + blockIdx.y) * gx + blockIdx.x;
    int cpx = nwg >> 3;
    int swz = (lin & 7) * cpx + (lin >> 3);
    const int bx = swz % gx;
    const int by = (swz / gx) % gy;
    const int b  = swz / (gx * gy);

    const int nBase = bx * 128;
    const int mBase = by * 128;
    const int tid   = threadIdx.x;
    const int lane  = tid & 63, wid = tid >> 6;
    const int wr    = wid >> 1, wc = wid & 1;

    __shared__ uint32_t Ah0[2048], Al0[2048], Bh0[2048], Bl0[2048];
    __shared__ uint32_t Ah1[2048], Al1[2048], Bh1[2048], Bl1[2048];

    const ushort* Abh = Aph + (size_t)b * aStride;
    const ushort* Abl = Apl + (size_t)b * aStride;
    const ushort* Bbh = Bph + (size_t)b * bStride;
    const ushort* Bbl = Bpl + (size_t)b * bStride;

    f32x4 acc[4][4];
#pragma unroll
    for (int i = 0; i < 4; ++i)
#pragma unroll
        for (int j = 0; j < 4; ++j) acc[i][j] = (f32x4){0.f, 0.f, 0.f, 0.f};

    const int fr = lane & 15;
    const int kc = lane >> 4;                 // k-chunk 0..3 (8 bf16 each)

    STAGE_TILE(Ah0, Al0, Bh0, Bl0, 0);
    __syncthreads();

#pragma unroll 1
    for (int it2 = 0; it2 < 8; ++it2) {
        const int ktE1 = it2 * 64 + 32;       // odd tile, bf16-element offset
        STAGE_TILE(Ah1, Al1, Bh1, Bl1, ktE1);
        COMPUTE_TILE(Ah0, Al0, Bh0, Bl0);
        __syncthreads();
        if (it2 < 7) {
            STAGE_TILE(Ah0, Al0, Bh0, Bl0, ktE1 + 32);
        }
        COMPUTE_TILE(Ah1, Al1, Bh1, Bl1);
        __syncthreads();
    }

    // epilogue. C/D layout: col(n) = lane&15, row(m) = (lane>>4)*4 + reg
    const int rrow = (lane >> 4) * 4;
    if constexpr (MODE == 0) {
#pragma unroll
        for (int fn = 0; fn < 4; ++fn) {
            int o = nBase + wc * 64 + fn * 16 + fr;
            float bo  = bias[o];
            float pco = aux[(size_t)b * CC + o];
#pragma unroll
            for (int fm = 0; fm < 4; ++fm) {
#pragma unroll
                for (int r = 0; r < 4; ++r) {
                    int p = mBase + wr * 64 + fm * 16 + rrow + r;
                    size_t idx = (size_t)p * CC + o;
                    float fs = joinbf(Abh[idx], Abl[idx]);
                    float z = acc[fm][fn][r] + bo;
                    float g = 1.f / (1.f + expf(-z));
                    uint32_t u = packbf(fs + g * pco);
                    size_t gidx = (size_t)b * NPIX * CC + idx;
                    oh[gidx] = (ushort)(u >> 16);
                    ol[gidx] = (ushort)(u & 0xffffu);
                }
            }
        }
    } else {
#pragma unroll
        for (int fn = 0; fn < 4; ++fn) {
            int p = nBase + wc * 64 + fn * 16 + fr;
            float dv = aux[(size_t)b * NPIX + p];
#pragma unroll
            for (int fm = 0; fm < 4; ++fm) {
#pragma unroll
                for (int r = 0; r < 4; ++r) {
                    int o = mBase + wr * 64 + fm * 16 + rrow + r;
                    float z = acc[fm][fn][r] + bias[o] + wsrc[(size_t)o * (CC + 1) + CC] * dv;
                    of[((size_t)b * CC + o) * NPIX + p] = fmaxf(z, 0.f);
                }
            }
        }
    }
}

extern "C" void kernel_launch(void* const* d_in, const int* in_sizes, int n_in,
                              void* d_out, int out_size, void* d_ws, size_t ws_size,
                              hipStream_t stream)
{
    const float* f_s      = (const float*)d_in[0];
    const int*   mask     = (const int*)d_in[1];
    const float* gate_w   = (const float*)d_in[2];
    const float* gate_b   = (const float*)d_in[3];
    const float* fusion_w = (const float*)d_in[4];
    const float* fusion_b = (const float*)d_in[5];
    float* out = (float*)d_out;
    float*  wsf = (float*)d_ws;
    uint32_t* wsu = (uint32_t*)d_ws;

    float* ms   = wsf + WS_MS;
    float* mbg  = wsf + WS_MBG;
    float* dist = wsf + WS_DIST;
    float* cnt  = wsf + WS_CNT;
    float* pc   = wsf + WS_PC;
    ushort* gwh = (ushort*)(wsu + WS_GWH);
    ushort* gwl = (ushort*)(wsu + WS_GWL);
    ushort* fwh = (ushort*)(wsu + WS_FWH);
    ushort* fwl = (ushort*)(wsu + WS_FWL);
    ushort* fsh = (ushort*)(wsu + WS_FSH);
    ushort* fsl = (ushort*)(wsu + WS_FSL);
    ushort* fph = (ushort*)(wsu + WS_FPH);
    ushort* fpl = (ushort*)(wsu + WS_FPL);

    hipLaunchKernelGGL(mask_edt_kernel, dim3(NB), dim3(1024), 0, stream,
                       mask, ms, mbg, dist, cnt);
    hipLaunchKernelGGL(pack_weights, dim3(CC), dim3(256), 0, stream,
                       gate_w, fusion_w, gwh, gwl, fwh, fwl);
    hipLaunchKernelGGL(transpose_pack, dim3(NPIX / 64, CC / 64, NB), dim3(256), 0, stream,
                       f_s, fsh, fsl);
    hipLaunchKernelGGL(pcontrast_kernel, dim3(CC, NB), dim3(256), 0, stream,
                       f_s, ms, mbg, cnt, pc);
    // GEMM-1: M=p (4096), N=o (512). A=f_s planes (batched), B=gate_w planes.
    hipLaunchKernelGGL((mfma_gemm<0>), dim3(CC / 128, NPIX / 128, NB), dim3(256), 0, stream,
                       fsh, fsl, gwh, gwl, (long)NPIX * CC, 0L, gate_b, pc,
                       (const float*)nullptr, fph, fpl, (float*)nullptr);
    // GEMM-2: M=o (512), N=p (4096). A=fusion_w planes, B=f_pur planes (batched).
    hipLaunchKernelGGL((mfma_gemm<1>), dim3(NPIX / 128, CC / 128, NB), dim3(256), 0, stream,
                       fwh, fwl, fph, fpl, 0L, (long)NPIX * CC, fusion_b, dist,
                       fusion_w, (ushort*)nullptr, (ushort*)nullptr, out);
}